// Round 2
// baseline (1314.865 us; speedup 1.0000x reference)
//
#include <hip/hip_runtime.h>
#include <hip/hip_bf16.h>

#define NN 50000
#define NE 600000
#define DD 128
#define RB 40            // rows per block in fused kernel (50000 = 1250 * 40)
#define RG 20            // rows per thread-group (2 groups of 128 threads)

// ---------------- scatter: agg[dst] += nodes[src]  (fp32) ----------------
__global__ __launch_bounds__(256) void scatter_k(
    const float* __restrict__ nodes,
    const int* __restrict__ adj,        // [2, NE]: row 0 = dst, row 1 = src
    float* __restrict__ agg)
{
    int idx = blockIdx.x * 256 + threadIdx.x;
    int e = idx >> 5;                   // 32 threads per edge, 4 channels each
    if (e >= NE) return;
    int c = (idx & 31) << 2;
    int d = adj[e];
    int s = adj[NE + e];
    const float4 v = *reinterpret_cast<const float4*>(nodes + (size_t)s * DD + c);
    float* o = agg + (size_t)d * DD + c;
    atomicAdd(o + 0, v.x);
    atomicAdd(o + 1, v.y);
    atomicAdd(o + 2, v.z);
    atomicAdd(o + 3, v.w);
}

// ---------------- fused: softmax -> gates -> output ----------------
__global__ __launch_bounds__(256) void fused_k(
    const float* __restrict__ nodes,
    const float* __restrict__ agg,
    const float* __restrict__ bias,
    const float* __restrict__ Wr, const float* __restrict__ br,
    const float* __restrict__ Wz, const float* __restrict__ bz,
    const float* __restrict__ Wt, const float* __restrict__ bt,
    float* __restrict__ out)
{
    __shared__ float A[RB][256];        // [s (128) | prior_h -> r*prior_h (128)] per row; 40 KB
    const int tid  = threadIdx.x;
    const int row0 = blockIdx.x * RB;
    const int wave = tid >> 6, lane = tid & 63;

    // Phase A: per-row softmax(agg + bias), stage s and prior_h into LDS
    {
        float bias0 = bias[lane], bias1 = bias[lane + 64];
        for (int j = 0; j < RB / 4; ++j) {
            int r = wave * (RB / 4) + j;
            int grow = row0 + r;
            float x0 = agg[(size_t)grow * DD + lane]      + bias0;
            float x1 = agg[(size_t)grow * DD + lane + 64] + bias1;
            float m = fmaxf(x0, x1);
#pragma unroll
            for (int o = 32; o > 0; o >>= 1) m = fmaxf(m, __shfl_xor(m, o));
            float e0 = __expf(x0 - m), e1 = __expf(x1 - m);
            float sm = e0 + e1;
#pragma unroll
            for (int o = 32; o > 0; o >>= 1) sm += __shfl_xor(sm, o);
            float inv = 1.0f / sm;
            A[r][lane]       = e0 * inv;
            A[r][lane + 64]  = e1 * inv;
            A[r][128 + lane]      = nodes[(size_t)grow * DD + lane];
            A[r][128 + lane + 64] = nodes[(size_t)grow * DD + lane + 64];
        }
    }
    __syncthreads();

    const int col   = tid & 127;
    const int g     = tid >> 7;
    const int rbase = g * RG;

    // Step 1: pre_r, pre_z = [s | ph] @ {Wr, Wz} + b
    float accr[RG], accz[RG];
    {
        float brc = br[col], bzc = bz[col];
#pragma unroll
        for (int i = 0; i < RG; ++i) { accr[i] = brc; accz[i] = bzc; }
    }
    for (int k4 = 0; k4 < 64; ++k4) {
        int k = k4 * 4;
        float wr0 = Wr[(k + 0) * DD + col];
        float wr1 = Wr[(k + 1) * DD + col];
        float wr2 = Wr[(k + 2) * DD + col];
        float wr3 = Wr[(k + 3) * DD + col];
        float wz0 = Wz[(k + 0) * DD + col];
        float wz1 = Wz[(k + 1) * DD + col];
        float wz2 = Wz[(k + 2) * DD + col];
        float wz3 = Wz[(k + 3) * DD + col];
#pragma unroll
        for (int i = 0; i < RG; ++i) {
            float4 a = *reinterpret_cast<const float4*>(&A[rbase + i][k]);
            accr[i] = fmaf(a.x, wr0, accr[i]);
            accr[i] = fmaf(a.y, wr1, accr[i]);
            accr[i] = fmaf(a.z, wr2, accr[i]);
            accr[i] = fmaf(a.w, wr3, accr[i]);
            accz[i] = fmaf(a.x, wz0, accz[i]);
            accz[i] = fmaf(a.y, wz1, accz[i]);
            accz[i] = fmaf(a.z, wz2, accz[i]);
            accz[i] = fmaf(a.w, wz3, accz[i]);
        }
    }

    // Gates; overwrite ph half of LDS with r * ph
    float zv[RG], rph[RG];
#pragma unroll
    for (int i = 0; i < RG; ++i) {
        float rr = 1.0f / (1.0f + __expf(-accr[i]));
        zv[i]    = 1.0f / (1.0f + __expf(-accz[i]));
        rph[i]   = rr * A[rbase + i][128 + col];
    }
    __syncthreads();
#pragma unroll
    for (int i = 0; i < RG; ++i) A[rbase + i][128 + col] = rph[i];
    __syncthreads();

    // Step 2: pre_t = [s | r*ph] @ Wt + bt
    float acct[RG];
    {
        float btc = bt[col];
#pragma unroll
        for (int i = 0; i < RG; ++i) acct[i] = btc;
    }
    for (int k4 = 0; k4 < 64; ++k4) {
        int k = k4 * 4;
        float wt0 = Wt[(k + 0) * DD + col];
        float wt1 = Wt[(k + 1) * DD + col];
        float wt2 = Wt[(k + 2) * DD + col];
        float wt3 = Wt[(k + 3) * DD + col];
#pragma unroll
        for (int i = 0; i < RG; ++i) {
            float4 a = *reinterpret_cast<const float4*>(&A[rbase + i][k]);
            acct[i] = fmaf(a.x, wt0, acct[i]);
            acct[i] = fmaf(a.y, wt1, acct[i]);
            acct[i] = fmaf(a.z, wt2, acct[i]);
            acct[i] = fmaf(a.w, wt3, acct[i]);
        }
    }

    // Epilogue: h = (1-z)*ph + z*tanh(pre_t)
#pragma unroll
    for (int i = 0; i < RG; ++i) {
        int grow = row0 + rbase + i;
        float ph = nodes[(size_t)grow * DD + col];
        float hh = tanhf(acct[i]);
        float h  = (1.0f - zv[i]) * ph + zv[i] * hh;
        out[(size_t)grow * DD + col] = h;
    }
}

extern "C" void kernel_launch(void* const* d_in, const int* in_sizes, int n_in,
                              void* d_out, int out_size, void* d_ws, size_t ws_size,
                              hipStream_t stream) {
    const float* nodes = (const float*)d_in[0];
    const int*   adj   = (const int*)d_in[1];
    const float* bias  = (const float*)d_in[2];
    const float* Wr    = (const float*)d_in[3];
    const float* br    = (const float*)d_in[4];
    const float* Wz    = (const float*)d_in[5];
    const float* bz    = (const float*)d_in[6];
    const float* Wt    = (const float*)d_in[7];
    const float* bt    = (const float*)d_in[8];
    float* out = (float*)d_out;

    float* agg = (float*)d_ws;                       // [NN, DD] fp32 accumulator

    hipMemsetAsync(agg, 0, (size_t)NN * DD * sizeof(float), stream);

    // Reference loop never updates prior_h, so all 4 steps compute the same h:
    // one propagation step is sufficient.
    int scatter_threads = NE * 32;
    scatter_k<<<(scatter_threads + 255) / 256, 256, 0, stream>>>(nodes, adj, agg);
    fused_k<<<NN / RB, 256, 0, stream>>>(nodes, agg, bias, Wr, br, Wz, bz, Wt, bt, out);
}

// Round 3
// 393.789 us; speedup vs baseline: 3.3390x; 3.3390x over previous
//
#include <hip/hip_runtime.h>

#define NN 50000
#define NE 600000
#define DD 128
#define RB 40            // rows per block in fused kernel (50000 = 1250 * 40)
#define RG 20            // rows per thread-group (2 groups of 128 threads)

// d_ws layout (bytes):
//   [0, 256K)            : int cnt[NN]      (padded region, memset to 0)
//   [256K, 256K+25.6M)   : float agg[NN*DD] (overflow base, memset to 0)
//   [256K+25.6M, ...)    : int slots[NN*CAP]
#define CNT_BYTES  262144
#define AGG_BYTES  (NN * DD * 4)
#define SLOT_OFF   (CNT_BYTES + AGG_BYTES)

// ---------------- fill: bucket edges by dst ----------------
__global__ __launch_bounds__(256) void fill_k(
    const float* __restrict__ nodes,
    const int* __restrict__ adj,        // [2, NE]: row 0 = dst, row 1 = src
    int* __restrict__ cnt,
    int* __restrict__ slots,
    float* __restrict__ agg,
    int cap)
{
    int e = blockIdx.x * 256 + threadIdx.x;
    if (e >= NE) return;
    int d = adj[e];
    int s = adj[NE + e];
    int pos = atomicAdd(&cnt[d], 1);
    if (pos < cap) {
        slots[(size_t)d * cap + pos] = s;
    } else {
        // overflow (statistically ~never at cap=64): accumulate directly
        const float* src = nodes + (size_t)s * DD;
        float* o = agg + (size_t)d * DD;
        for (int c = 0; c < DD; ++c) atomicAdd(o + c, src[c]);
    }
}

// ---------------- fallback scatter (used only if ws too small) ----------------
__global__ __launch_bounds__(256) void scatter_k(
    const float* __restrict__ nodes,
    const int* __restrict__ adj,
    float* __restrict__ agg)
{
    int idx = blockIdx.x * 256 + threadIdx.x;
    int e = idx >> 5;
    if (e >= NE) return;
    int c = (idx & 31) << 2;
    int d = adj[e];
    int s = adj[NE + e];
    const float4 v = *reinterpret_cast<const float4*>(nodes + (size_t)s * DD + c);
    float* o = agg + (size_t)d * DD + c;
    atomicAdd(o + 0, v.x);
    atomicAdd(o + 1, v.y);
    atomicAdd(o + 2, v.z);
    atomicAdd(o + 3, v.w);
}

// ---------------- fused: gather -> softmax -> gates -> output ----------------
__global__ __launch_bounds__(256) void fused_k(
    const float* __restrict__ nodes,
    const int* __restrict__ cnt,
    const int* __restrict__ slots,
    const float* __restrict__ agg,
    const float* __restrict__ bias,
    const float* __restrict__ Wr, const float* __restrict__ br,
    const float* __restrict__ Wz, const float* __restrict__ bz,
    const float* __restrict__ Wt, const float* __restrict__ bt,
    float* __restrict__ out,
    int cap)                            // cap = -1 => agg-only mode (fallback)
{
    __shared__ float A[RB][256];        // [s (128) | prior_h -> r*prior_h (128)] per row; 40 KB
    const int tid  = threadIdx.x;
    const int row0 = blockIdx.x * RB;
    const int wave = tid >> 6, lane = tid & 63;

    // Phase A: gather agg[dst] = sum nodes[src], then softmax(agg + bias)
    {
        float bias0 = bias[lane], bias1 = bias[lane + 64];
        for (int j = 0; j < RB / 4; ++j) {
            int r = wave * (RB / 4) + j;
            int grow = row0 + r;
            int c  = cnt[grow];                 // wave-uniform
            int cs = min(c, cap);
            float x0, x1;
            if (c > cap) {                      // overflow base (or fallback mode)
                x0 = agg[(size_t)grow * DD + lane];
                x1 = agg[(size_t)grow * DD + lane + 64];
            } else {
                x0 = 0.0f; x1 = 0.0f;
            }
            int myslot = (lane < cs) ? slots[(size_t)grow * cap + lane] : 0;
            int jj = 0;
            for (; jj + 1 < cs; jj += 2) {      // 2-way unrolled gather, 4 loads in flight
                int s0 = __shfl(myslot, jj);
                int s1 = __shfl(myslot, jj + 1);
                const float* p0 = nodes + (size_t)s0 * DD;
                const float* p1 = nodes + (size_t)s1 * DD;
                float a0 = p0[lane], a1 = p0[lane + 64];
                float b0 = p1[lane], b1 = p1[lane + 64];
                x0 += a0 + b0;
                x1 += a1 + b1;
            }
            if (jj < cs) {
                int s0 = __shfl(myslot, jj);
                const float* p0 = nodes + (size_t)s0 * DD;
                x0 += p0[lane];
                x1 += p0[lane + 64];
            }
            x0 += bias0; x1 += bias1;
            float m = fmaxf(x0, x1);
#pragma unroll
            for (int o = 32; o > 0; o >>= 1) m = fmaxf(m, __shfl_xor(m, o));
            float e0 = __expf(x0 - m), e1 = __expf(x1 - m);
            float sm = e0 + e1;
#pragma unroll
            for (int o = 32; o > 0; o >>= 1) sm += __shfl_xor(sm, o);
            float inv = 1.0f / sm;
            A[r][lane]       = e0 * inv;
            A[r][lane + 64]  = e1 * inv;
            A[r][128 + lane]      = nodes[(size_t)grow * DD + lane];
            A[r][128 + lane + 64] = nodes[(size_t)grow * DD + lane + 64];
        }
    }
    __syncthreads();

    const int col   = tid & 127;
    const int g     = tid >> 7;
    const int rbase = g * RG;

    // Step 1: pre_r, pre_z = [s | ph] @ {Wr, Wz} + b
    float accr[RG], accz[RG];
    {
        float brc = br[col], bzc = bz[col];
#pragma unroll
        for (int i = 0; i < RG; ++i) { accr[i] = brc; accz[i] = bzc; }
    }
    for (int k4 = 0; k4 < 64; ++k4) {
        int k = k4 * 4;
        float wr0 = Wr[(k + 0) * DD + col];
        float wr1 = Wr[(k + 1) * DD + col];
        float wr2 = Wr[(k + 2) * DD + col];
        float wr3 = Wr[(k + 3) * DD + col];
        float wz0 = Wz[(k + 0) * DD + col];
        float wz1 = Wz[(k + 1) * DD + col];
        float wz2 = Wz[(k + 2) * DD + col];
        float wz3 = Wz[(k + 3) * DD + col];
#pragma unroll
        for (int i = 0; i < RG; ++i) {
            float4 a = *reinterpret_cast<const float4*>(&A[rbase + i][k]);
            accr[i] = fmaf(a.x, wr0, accr[i]);
            accr[i] = fmaf(a.y, wr1, accr[i]);
            accr[i] = fmaf(a.z, wr2, accr[i]);
            accr[i] = fmaf(a.w, wr3, accr[i]);
            accz[i] = fmaf(a.x, wz0, accz[i]);
            accz[i] = fmaf(a.y, wz1, accz[i]);
            accz[i] = fmaf(a.z, wz2, accz[i]);
            accz[i] = fmaf(a.w, wz3, accz[i]);
        }
    }

    // Gates; overwrite ph half of LDS with r * ph
    float zv[RG], rph[RG];
#pragma unroll
    for (int i = 0; i < RG; ++i) {
        float rr = 1.0f / (1.0f + __expf(-accr[i]));
        zv[i]    = 1.0f / (1.0f + __expf(-accz[i]));
        rph[i]   = rr * A[rbase + i][128 + col];
    }
    __syncthreads();
#pragma unroll
    for (int i = 0; i < RG; ++i) A[rbase + i][128 + col] = rph[i];
    __syncthreads();

    // Step 2: pre_t = [s | r*ph] @ Wt + bt
    float acct[RG];
    {
        float btc = bt[col];
#pragma unroll
        for (int i = 0; i < RG; ++i) acct[i] = btc;
    }
    for (int k4 = 0; k4 < 64; ++k4) {
        int k = k4 * 4;
        float wt0 = Wt[(k + 0) * DD + col];
        float wt1 = Wt[(k + 1) * DD + col];
        float wt2 = Wt[(k + 2) * DD + col];
        float wt3 = Wt[(k + 3) * DD + col];
#pragma unroll
        for (int i = 0; i < RG; ++i) {
            float4 a = *reinterpret_cast<const float4*>(&A[rbase + i][k]);
            acct[i] = fmaf(a.x, wt0, acct[i]);
            acct[i] = fmaf(a.y, wt1, acct[i]);
            acct[i] = fmaf(a.z, wt2, acct[i]);
            acct[i] = fmaf(a.w, wt3, acct[i]);
        }
    }

    // Epilogue: h = (1-z)*ph + z*tanh(pre_t)
#pragma unroll
    for (int i = 0; i < RG; ++i) {
        int grow = row0 + rbase + i;
        float ph = nodes[(size_t)grow * DD + col];
        float hh = tanhf(acct[i]);
        float h  = (1.0f - zv[i]) * ph + zv[i] * hh;
        out[(size_t)grow * DD + col] = h;
    }
}

extern "C" void kernel_launch(void* const* d_in, const int* in_sizes, int n_in,
                              void* d_out, int out_size, void* d_ws, size_t ws_size,
                              hipStream_t stream) {
    const float* nodes = (const float*)d_in[0];
    const int*   adj   = (const int*)d_in[1];
    const float* bias  = (const float*)d_in[2];
    const float* Wr    = (const float*)d_in[3];
    const float* br    = (const float*)d_in[4];
    const float* Wz    = (const float*)d_in[5];
    const float* bz    = (const float*)d_in[6];
    const float* Wt    = (const float*)d_in[7];
    const float* bt    = (const float*)d_in[8];
    float* out = (float*)d_out;

    char* ws = (char*)d_ws;
    int*   cnt   = (int*)ws;
    float* agg   = (float*)(ws + CNT_BYTES);
    int*   slots = (int*)(ws + SLOT_OFF);

    // Capacity per node bucket, limited by available workspace
    int cap = 0;
    if (ws_size > (size_t)SLOT_OFF) {
        size_t room = (ws_size - SLOT_OFF) / ((size_t)NN * sizeof(int));
        cap = (int)(room < 64 ? room : 64);
    }

    // zero cnt + agg
    hipMemsetAsync(ws, 0, CNT_BYTES + AGG_BYTES, stream);

    // Reference loop never updates prior_h, so all 4 steps compute the same h:
    // one propagation step is sufficient.
    if (cap >= 8) {
        fill_k<<<(NE + 255) / 256, 256, 0, stream>>>(nodes, adj, cnt, slots, agg, cap);
        fused_k<<<NN / RB, 256, 0, stream>>>(nodes, cnt, slots, agg, bias,
                                             Wr, br, Wz, bz, Wt, bt, out, cap);
    } else {
        // workspace too small for buckets: old atomic-scatter path
        scatter_k<<<(NE * 32 + 255) / 256, 256, 0, stream>>>(nodes, adj, agg);
        fused_k<<<NN / RB, 256, 0, stream>>>(nodes, cnt, slots, agg, bias,
                                             Wr, br, Wz, bz, Wt, bt, out, -1);
    }
}

// Round 4
// 276.383 us; speedup vs baseline: 4.7574x; 1.4248x over previous
//
#include <hip/hip_runtime.h>

#define NN 50000
#define NE 600000
#define DD 128
#define CAP 64

typedef __attribute__((ext_vector_type(8))) short s16x8;   // 8 bf16 (4 VGPRs)
typedef __attribute__((ext_vector_type(4))) float f32x4;   // MFMA accumulator

// d_ws layout (bytes):
//   [0, 256K)        : int cnt[NN]                 (memset to 0 each launch)
//   [256K, +12.8M)   : int slots[NN*CAP]
//   [then, +192K)    : ushort wpack[3*8*8*512]     (B-fragment-packed bf16 weights)
#define CNT_BYTES  (256 * 1024)
#define SLOT_OFF   CNT_BYTES
#define SLOT_BYTES ((size_t)NN * CAP * 4)
#define WPACK_OFF  (SLOT_OFF + SLOT_BYTES)
#define WPACK_N    (3 * 8 * 8 * 512)            // 98304 ushort = 192 KB

__device__ __forceinline__ unsigned short f2bf(float f) {   // RNE fp32->bf16
    unsigned int u = __float_as_uint(f);
    unsigned int r = (u + 0x7fffu + ((u >> 16) & 1u)) >> 16;
    return (unsigned short)r;
}
__device__ __forceinline__ float bf2f(unsigned short h) {
    return __uint_as_float(((unsigned int)h) << 16);
}

// ---------------- fill: bucket edges by dst ----------------
__global__ __launch_bounds__(256) void fill_k(
    const int* __restrict__ adj, int* __restrict__ cnt, int* __restrict__ slots)
{
    int e = blockIdx.x * 256 + threadIdx.x;
    if (e >= NE) return;
    int d = adj[e];
    int pos = atomicAdd(&cnt[d], 1);
    if (pos < CAP) slots[d * CAP + pos] = adj[NE + e];
    // pos >= CAP: cnt[d] > CAP signals fused_k to take the full-scan path
}

// ---------------- convw: pack Wr/Wz/Wt into bf16 B-fragment order ----------------
// wpack[(((g*8+ct)*8+kt)*512) + l*8 + j] = bf16( Wg[k][col] )
//   k = kt*32 + ((l>>4)&3)*8 + j, col = ct*16 + (l&15)
__global__ __launch_bounds__(256) void convw_k(
    const float* __restrict__ Wr, const float* __restrict__ Wz,
    const float* __restrict__ Wt, unsigned short* __restrict__ wp)
{
    int t = blockIdx.x * 256 + threadIdx.x;      // [0, 98304)
    int j  = t & 7;
    int l  = (t >> 3) & 63;
    int kt = (t >> 9) & 7;
    int ct = (t >> 12) & 7;
    int g  = t >> 15;
    int k   = kt * 32 + ((l >> 4) & 3) * 8 + j;
    int col = ct * 16 + (l & 15);
    const float* W = (g == 0) ? Wr : (g == 1) ? Wz : Wt;
    wp[t] = f2bf(W[k * DD + col]);
}

// ---------------- fused: gather -> softmax -> 3 MFMA GEMMs -> output ----------------
__global__ __launch_bounds__(256) void fused_k(
    const float* __restrict__ nodes,
    const int* __restrict__ adj,
    const int* __restrict__ cnt,
    const int* __restrict__ slots,
    const unsigned short* __restrict__ wp,
    const float* __restrict__ bias,
    const float* __restrict__ br, const float* __restrict__ bz, const float* __restrict__ bt,
    float* __restrict__ out)
{
    // X[row][0:128]=s (bf16), X[row][128:256]=ph -> r*ph (bf16); +8 pad per row
    __shared__ unsigned short X[64][264];       // 33.8 KB
    const int tid  = threadIdx.x;
    const int w    = tid >> 6;                  // wave id: owns rows w*16..w*16+15
    const int l    = tid & 63;
    const int row0 = blockIdx.x * 64;

    // ---- Phase A: gather agg = sum nodes[src] (+bias), softmax, stage bf16 [s|ph]
    {
        float2 bb = *(const float2*)(bias + 2 * l);   // lane covers channels 2l, 2l+1
        for (int j = 0; j < 16; ++j) {
            int lr   = w * 16 + j;
            int grow = row0 + lr;
            int gc   = grow < NN ? grow : 0;
            int c    = cnt[gc];
            float x0 = 0.f, x1 = 0.f;
            if (c <= CAP) {
                int myslot = (l < c) ? slots[gc * CAP + l] : 0;
                int jj = 0;
                for (; jj + 3 < c; jj += 4) {       // 4-way MLP
                    int s0 = __shfl(myslot, jj),     s1 = __shfl(myslot, jj + 1);
                    int s2 = __shfl(myslot, jj + 2), s3 = __shfl(myslot, jj + 3);
                    float2 v0 = *(const float2*)(nodes + (size_t)s0 * DD + 2 * l);
                    float2 v1 = *(const float2*)(nodes + (size_t)s1 * DD + 2 * l);
                    float2 v2 = *(const float2*)(nodes + (size_t)s2 * DD + 2 * l);
                    float2 v3 = *(const float2*)(nodes + (size_t)s3 * DD + 2 * l);
                    x0 += v0.x + v1.x + v2.x + v3.x;
                    x1 += v0.y + v1.y + v2.y + v3.y;
                }
                for (; jj < c; ++jj) {
                    int s0 = __shfl(myslot, jj);
                    float2 v0 = *(const float2*)(nodes + (size_t)s0 * DD + 2 * l);
                    x0 += v0.x; x1 += v0.y;
                }
            } else {
                // overflow (prob ~0): correct full edge scan for this row
                for (int base = 0; base < NE; base += 64) {
                    int e  = base + l;
                    int d  = (e < NE) ? adj[e] : -1;
                    int sv = (e < NE) ? adj[NE + e] : 0;
                    unsigned long long m = __ballot(d == grow);
                    while (m) {
                        int b = __ffsll((unsigned long long)m) - 1;
                        m &= m - 1;
                        int s0 = __shfl(sv, b);
                        float2 v0 = *(const float2*)(nodes + (size_t)s0 * DD + 2 * l);
                        x0 += v0.x; x1 += v0.y;
                    }
                }
            }
            x0 += bb.x; x1 += bb.y;
            float mx = fmaxf(x0, x1);
#pragma unroll
            for (int o = 32; o > 0; o >>= 1) mx = fmaxf(mx, __shfl_xor(mx, o));
            float e0 = __expf(x0 - mx), e1 = __expf(x1 - mx);
            float sm = e0 + e1;
#pragma unroll
            for (int o = 32; o > 0; o >>= 1) sm += __shfl_xor(sm, o);
            float inv = 1.f / sm;
            *(unsigned int*)&X[lr][2 * l] =
                (unsigned)f2bf(e0 * inv) | ((unsigned)f2bf(e1 * inv) << 16);
            float2 ph = *(const float2*)(nodes + (size_t)gc * DD + 2 * l);
            *(unsigned int*)&X[lr][128 + 2 * l] =
                (unsigned)f2bf(ph.x) | ((unsigned)f2bf(ph.y) << 16);
        }
    }
    // NO __syncthreads: each wave reads only the 16 rows it just wrote.

    // ---- Phase B: MFMA GEMMs. Wave w owns row tile rt=w.
    const int rbase  = w * 16;
    const int mrow   = l & 15;      // A-frag row within tile
    const int quad   = l >> 4;      // A/B-frag k-quad
    const int col_in = l & 15;      // C/D col within tile
    const int rq     = l >> 4;      // C/D row quad

    s16x8 a[8];                      // A-frags for K=256 (8 x 32)
#pragma unroll
    for (int kt = 0; kt < 8; ++kt)
        a[kt] = *(const s16x8*)&X[rbase + mrow][kt * 32 + quad * 8];

    const s16x8* wp8 = (const s16x8*)wp;
    float zv[8][4];

    // r and z over all 8 col-tiles; write r*ph back into X ph-half
#pragma unroll
    for (int ct = 0; ct < 8; ++ct) {
        int c = ct * 16 + col_in;
        float brv = br[c], bzv = bz[c];
        f32x4 ar = {brv, brv, brv, brv};
        f32x4 az = {bzv, bzv, bzv, bzv};
#pragma unroll
        for (int kt = 0; kt < 8; ++kt) {
            s16x8 bfr = wp8[((0 * 8 + ct) * 8 + kt) * 64 + l];
            s16x8 bfz = wp8[((1 * 8 + ct) * 8 + kt) * 64 + l];
            ar = __builtin_amdgcn_mfma_f32_16x16x32_bf16(a[kt], bfr, ar, 0, 0, 0);
            az = __builtin_amdgcn_mfma_f32_16x16x32_bf16(a[kt], bfz, az, 0, 0, 0);
        }
#pragma unroll
        for (int i = 0; i < 4; ++i) {
            float rr = 1.f / (1.f + __expf(-ar[i]));
            zv[ct][i] = 1.f / (1.f + __expf(-az[i]));
            int lr = rbase + rq * 4 + i;
            float ph = bf2f(X[lr][128 + c]);
            X[lr][128 + c] = f2bf(rr * ph);       // same-wave rows only
        }
    }

    // reload A-frags covering the (now r*ph) half
#pragma unroll
    for (int kt = 4; kt < 8; ++kt)
        a[kt] = *(const s16x8*)&X[rbase + mrow][kt * 32 + quad * 8];

    // t GEMM + epilogue
#pragma unroll
    for (int ct = 0; ct < 8; ++ct) {
        int c = ct * 16 + col_in;
        float btv = bt[c];
        f32x4 at = {btv, btv, btv, btv};
#pragma unroll
        for (int kt = 0; kt < 8; ++kt) {
            s16x8 bft = wp8[((2 * 8 + ct) * 8 + kt) * 64 + l];
            at = __builtin_amdgcn_mfma_f32_16x16x32_bf16(a[kt], bft, at, 0, 0, 0);
        }
#pragma unroll
        for (int i = 0; i < 4; ++i) {
            int lr   = rbase + rq * 4 + i;
            int grow = row0 + lr;
            if (grow < NN) {
                float hh = tanhf(at[i]);
                float z  = zv[ct][i];
                float ph = nodes[(size_t)grow * DD + c];
                out[(size_t)grow * DD + c] = (1.f - z) * ph + z * hh;
            }
        }
    }
}

extern "C" void kernel_launch(void* const* d_in, const int* in_sizes, int n_in,
                              void* d_out, int out_size, void* d_ws, size_t ws_size,
                              hipStream_t stream) {
    const float* nodes = (const float*)d_in[0];
    const int*   adj   = (const int*)d_in[1];
    const float* bias  = (const float*)d_in[2];
    const float* Wr    = (const float*)d_in[3];
    const float* br    = (const float*)d_in[4];
    const float* Wz    = (const float*)d_in[5];
    const float* bz    = (const float*)d_in[6];
    const float* Wt    = (const float*)d_in[7];
    const float* bt    = (const float*)d_in[8];
    float* out = (float*)d_out;

    char* ws = (char*)d_ws;
    int*            cnt   = (int*)ws;
    int*            slots = (int*)(ws + SLOT_OFF);
    unsigned short* wpack = (unsigned short*)(ws + WPACK_OFF);
    // ws need: ~13.25 MB; round-3 run demonstrated ws_size >= ~27.5 MB.

    hipMemsetAsync(cnt, 0, (size_t)NN * sizeof(int), stream);

    // Reference never updates prior_h inside its loop -> all 4 steps identical;
    // one propagation step suffices.
    fill_k<<<(NE + 255) / 256, 256, 0, stream>>>(adj, cnt, slots);
    convw_k<<<WPACK_N / 256, 256, 0, stream>>>(Wr, Wz, Wt, wpack);
    fused_k<<<(NN + 63) / 64, 256, 0, stream>>>(nodes, adj, cnt, slots, wpack,
                                                bias, br, bz, bt, out);
}

// Round 5
// 273.719 us; speedup vs baseline: 4.8037x; 1.0097x over previous
//
#include <hip/hip_runtime.h>

#define NN 50000
#define NE 600000
#define DD 128
#define CAP 64

typedef __attribute__((ext_vector_type(8))) short s16x8;   // 8 bf16 (4 VGPRs)
typedef __attribute__((ext_vector_type(4))) float f32x4;   // MFMA accumulator

// d_ws layout (bytes):
//   [0, 256K)        : int cnt[NN]                 (memset to 0 each launch)
//   [256K, +12.8M)   : int slots[NN*CAP]
//   [then, +192K)    : ushort wpack[3*8*8*512]     (B-fragment-packed bf16 weights)
#define CNT_BYTES  (256 * 1024)
#define SLOT_OFF   CNT_BYTES
#define SLOT_BYTES ((size_t)NN * CAP * 4)
#define WPACK_OFF  (SLOT_OFF + SLOT_BYTES)
#define WPACK_N    (3 * 8 * 8 * 512)            // 98304 ushort = 192 KB

#define FILL_BLOCKS ((NE + 255) / 256)          // 2344
#define CONV_BLOCKS (WPACK_N / 256)             // 384

__device__ __forceinline__ unsigned short f2bf(float f) {   // RNE fp32->bf16
    unsigned int u = __float_as_uint(f);
    unsigned int r = (u + 0x7fffu + ((u >> 16) & 1u)) >> 16;
    return (unsigned short)r;
}
__device__ __forceinline__ float bf2f(unsigned short h) {
    return __uint_as_float(((unsigned int)h) << 16);
}

// ---------------- prep: bucket edges by dst + pack weights (merged) ----------------
__global__ __launch_bounds__(256) void prep_k(
    const int* __restrict__ adj, int* __restrict__ cnt, int* __restrict__ slots,
    const float* __restrict__ Wr, const float* __restrict__ Wz,
    const float* __restrict__ Wt, unsigned short* __restrict__ wp)
{
    int b = blockIdx.x;
    if (b < FILL_BLOCKS) {
        int e = b * 256 + threadIdx.x;
        if (e >= NE) return;
        int d = adj[e];
        int pos = atomicAdd(&cnt[d], 1);
        if (pos < CAP) slots[d * CAP + pos] = adj[NE + e];
        // pos >= CAP: cnt[d] > CAP signals fused_k to take the full-scan path
    } else {
        int t = (b - FILL_BLOCKS) * 256 + threadIdx.x;   // [0, 98304)
        int j  = t & 7;
        int l  = (t >> 3) & 63;
        int kt = (t >> 9) & 7;
        int ct = (t >> 12) & 7;
        int g  = t >> 15;
        int k   = kt * 32 + ((l >> 4) & 3) * 8 + j;
        int col = ct * 16 + (l & 15);
        const float* W = (g == 0) ? Wr : (g == 1) ? Wz : Wt;
        wp[t] = f2bf(W[k * DD + col]);
    }
}

// ---------------- fused: gather -> softmax -> 3 MFMA GEMMs -> output ----------------
__global__ __launch_bounds__(256) void fused_k(
    const float* __restrict__ nodes,
    const int* __restrict__ adj,
    const int* __restrict__ cnt,
    const int* __restrict__ slots,
    const unsigned short* __restrict__ wp,
    const float* __restrict__ bias,
    const float* __restrict__ br, const float* __restrict__ bz, const float* __restrict__ bt,
    float* __restrict__ out)
{
    // X[row][0:128]=s (bf16), X[row][128:256]=ph -> r*ph (bf16); +8 pad per row
    __shared__ unsigned short X[64][264];       // 33.8 KB
    const int tid  = threadIdx.x;
    const int w    = tid >> 6;                  // wave id: owns rows w*16..w*16+15
    const int l    = tid & 63;
    const int row0 = blockIdx.x * 64;

    // ---- Phase A: gather agg = sum nodes[src] (+bias), softmax, stage bf16 [s|ph]
    // Half-wave mapping: lane l covers channels 4*(l&31)..+3; one float4 load
    // instruction fetches TWO source rows (lanes 0-31 = slot jj, 32-63 = jj+1).
    {
        const int half = l >> 5;
        const int li   = l & 31;
        const float4 bb = *(const float4*)(bias + 4 * li);
        for (int j = 0; j < 16; ++j) {
            int lr   = w * 16 + j;
            int grow = row0 + lr;
            int gc   = grow < NN ? grow : 0;
            int c    = cnt[gc];
            float x0 = 0.f, x1 = 0.f, x2 = 0.f, x3 = 0.f;
            if (c <= CAP) {
                int myslot = (l < c) ? slots[gc * CAP + l] : 0;
                int jj = 0;
                for (; jj + 7 < c; jj += 8) {       // 8 source rows in flight
                    int s0 = __shfl(myslot, jj     + half);
                    int s1 = __shfl(myslot, jj + 2 + half);
                    int s2 = __shfl(myslot, jj + 4 + half);
                    int s3 = __shfl(myslot, jj + 6 + half);
                    float4 v0 = *(const float4*)(nodes + (size_t)s0 * DD + 4 * li);
                    float4 v1 = *(const float4*)(nodes + (size_t)s1 * DD + 4 * li);
                    float4 v2 = *(const float4*)(nodes + (size_t)s2 * DD + 4 * li);
                    float4 v3 = *(const float4*)(nodes + (size_t)s3 * DD + 4 * li);
                    x0 += v0.x + v1.x + v2.x + v3.x;
                    x1 += v0.y + v1.y + v2.y + v3.y;
                    x2 += v0.z + v1.z + v2.z + v3.z;
                    x3 += v0.w + v1.w + v2.w + v3.w;
                }
                for (; jj < c; jj += 2) {           // tail, predicated per half
                    int idx  = jj + half;
                    int sidx = idx < c ? idx : 0;
                    int s0   = __shfl(myslot, sidx);
                    if (idx < c) {
                        float4 v0 = *(const float4*)(nodes + (size_t)s0 * DD + 4 * li);
                        x0 += v0.x; x1 += v0.y; x2 += v0.z; x3 += v0.w;
                    }
                }
            } else {
                // overflow (prob ~0): full edge scan; halves take alternate matches
                int mi = 0;
                for (int base = 0; base < NE; base += 64) {
                    int e  = base + l;
                    int d  = (e < NE) ? adj[e] : -1;
                    int sv = (e < NE) ? adj[NE + e] : 0;
                    unsigned long long m = __ballot(d == grow);
                    while (m) {
                        int b = __ffsll((unsigned long long)m) - 1;
                        m &= m - 1;
                        int s0 = __shfl(sv, b);
                        if ((mi & 1) == half) {
                            float4 v0 = *(const float4*)(nodes + (size_t)s0 * DD + 4 * li);
                            x0 += v0.x; x1 += v0.y; x2 += v0.z; x3 += v0.w;
                        }
                        ++mi;
                    }
                }
            }
            // combine the two half-wave partial sums
            x0 += __shfl_xor(x0, 32);
            x1 += __shfl_xor(x1, 32);
            x2 += __shfl_xor(x2, 32);
            x3 += __shfl_xor(x3, 32);
            x0 += bb.x; x1 += bb.y; x2 += bb.z; x3 += bb.w;
            float mx = fmaxf(fmaxf(x0, x1), fmaxf(x2, x3));
#pragma unroll
            for (int o = 16; o > 0; o >>= 1) mx = fmaxf(mx, __shfl_xor(mx, o));
            float e0 = __expf(x0 - mx), e1 = __expf(x1 - mx);
            float e2 = __expf(x2 - mx), e3 = __expf(x3 - mx);
            float sm = e0 + e1 + e2 + e3;
#pragma unroll
            for (int o = 16; o > 0; o >>= 1) sm += __shfl_xor(sm, o);
            float inv = 1.f / sm;
            if (half == 0) {                        // s-half: channels 4li..4li+3
                uint2 u;
                u.x = (unsigned)f2bf(e0 * inv) | ((unsigned)f2bf(e1 * inv) << 16);
                u.y = (unsigned)f2bf(e2 * inv) | ((unsigned)f2bf(e3 * inv) << 16);
                *(uint2*)&X[lr][4 * li] = u;
            } else {                                // ph-half
                float4 ph = *(const float4*)(nodes + (size_t)gc * DD + 4 * li);
                uint2 u;
                u.x = (unsigned)f2bf(ph.x) | ((unsigned)f2bf(ph.y) << 16);
                u.y = (unsigned)f2bf(ph.z) | ((unsigned)f2bf(ph.w) << 16);
                *(uint2*)&X[lr][128 + 4 * li] = u;
            }
        }
    }
    // NO __syncthreads: each wave reads only the 16 rows it just wrote.

    // ---- Phase B: MFMA GEMMs. Wave w owns row tile rt=w.
    const int rbase  = w * 16;
    const int mrow   = l & 15;      // A-frag row within tile
    const int quad   = l >> 4;      // A/B-frag k-quad
    const int col_in = l & 15;      // C/D col within tile
    const int rq     = l >> 4;      // C/D row quad

    s16x8 a[8];                      // A-frags for K=256 (8 x 32)
#pragma unroll
    for (int kt = 0; kt < 8; ++kt)
        a[kt] = *(const s16x8*)&X[rbase + mrow][kt * 32 + quad * 8];

    const s16x8* wp8 = (const s16x8*)wp;
    float zv[8][4];

    // r and z over all 8 col-tiles; write r*ph back into X ph-half
#pragma unroll
    for (int ct = 0; ct < 8; ++ct) {
        int c = ct * 16 + col_in;
        float brv = br[c], bzv = bz[c];
        f32x4 ar = {brv, brv, brv, brv};
        f32x4 az = {bzv, bzv, bzv, bzv};
#pragma unroll
        for (int kt = 0; kt < 8; ++kt) {
            s16x8 bfr = wp8[((0 * 8 + ct) * 8 + kt) * 64 + l];
            s16x8 bfz = wp8[((1 * 8 + ct) * 8 + kt) * 64 + l];
            ar = __builtin_amdgcn_mfma_f32_16x16x32_bf16(a[kt], bfr, ar, 0, 0, 0);
            az = __builtin_amdgcn_mfma_f32_16x16x32_bf16(a[kt], bfz, az, 0, 0, 0);
        }
#pragma unroll
        for (int i = 0; i < 4; ++i) {
            float rr = 1.f / (1.f + __expf(-ar[i]));
            zv[ct][i] = 1.f / (1.f + __expf(-az[i]));
            int lr = rbase + rq * 4 + i;
            float ph = bf2f(X[lr][128 + c]);
            X[lr][128 + c] = f2bf(rr * ph);       // same-wave rows only
        }
    }

    // reload A-frags covering the (now r*ph) half
#pragma unroll
    for (int kt = 4; kt < 8; ++kt)
        a[kt] = *(const s16x8*)&X[rbase + mrow][kt * 32 + quad * 8];

    // t GEMM + epilogue
#pragma unroll
    for (int ct = 0; ct < 8; ++ct) {
        int c = ct * 16 + col_in;
        float btv = bt[c];
        f32x4 at = {btv, btv, btv, btv};
#pragma unroll
        for (int kt = 0; kt < 8; ++kt) {
            s16x8 bft = wp8[((2 * 8 + ct) * 8 + kt) * 64 + l];
            at = __builtin_amdgcn_mfma_f32_16x16x32_bf16(a[kt], bft, at, 0, 0, 0);
        }
#pragma unroll
        for (int i = 0; i < 4; ++i) {
            int lr   = rbase + rq * 4 + i;
            int grow = row0 + lr;
            if (grow < NN) {
                float hh = tanhf(at[i]);
                float z  = zv[ct][i];
                float ph = nodes[(size_t)grow * DD + c];
                out[(size_t)grow * DD + c] = (1.f - z) * ph + z * hh;
            }
        }
    }
}

extern "C" void kernel_launch(void* const* d_in, const int* in_sizes, int n_in,
                              void* d_out, int out_size, void* d_ws, size_t ws_size,
                              hipStream_t stream) {
    const float* nodes = (const float*)d_in[0];
    const int*   adj   = (const int*)d_in[1];
    const float* bias  = (const float*)d_in[2];
    const float* Wr    = (const float*)d_in[3];
    const float* br    = (const float*)d_in[4];
    const float* Wz    = (const float*)d_in[5];
    const float* bz    = (const float*)d_in[6];
    const float* Wt    = (const float*)d_in[7];
    const float* bt    = (const float*)d_in[8];
    float* out = (float*)d_out;

    char* ws = (char*)d_ws;
    int*            cnt   = (int*)ws;
    int*            slots = (int*)(ws + SLOT_OFF);
    unsigned short* wpack = (unsigned short*)(ws + WPACK_OFF);

    hipMemsetAsync(cnt, 0, (size_t)NN * sizeof(int), stream);

    // Reference never updates prior_h inside its loop -> all 4 steps identical;
    // one propagation step suffices.
    prep_k<<<FILL_BLOCKS + CONV_BLOCKS, 256, 0, stream>>>(adj, cnt, slots,
                                                          Wr, Wz, Wt, wpack);
    fused_k<<<(NN + 63) / 64, 256, 0, stream>>>(nodes, adj, cnt, slots, wpack,
                                                bias, br, bz, bt, out);
}

// Round 6
// 244.624 us; speedup vs baseline: 5.3750x; 1.1189x over previous
//
#include <hip/hip_runtime.h>

#define NN 50000
#define NE 600000
#define DD 128
#define CAP 64

typedef __attribute__((ext_vector_type(8))) short s16x8;   // 8 bf16 (4 VGPRs)
typedef __attribute__((ext_vector_type(4))) float f32x4;   // MFMA accumulator

// d_ws layout (bytes):
//   [0, 256K)       : int cnt[NN]                (memset to 0 each launch)
//   [SLOT_OFF, +6.4M): ushort slots[NN*CAP]
//   [WPACK_OFF,+192K): ushort wpack[3*8*8*512]   (B-fragment-packed bf16 weights)
//   [NBF_OFF, +12.8M): ushort nbf[NN*DD]         (bf16 copy of nodes)
#define CNT_BYTES   (256 * 1024)
#define SLOT_OFF    CNT_BYTES
#define SLOT_BYTES  ((size_t)NN * CAP * 2)
#define WPACK_OFF   (SLOT_OFF + SLOT_BYTES)
#define WPACK_N     (3 * 8 * 8 * 512)           // 98304 ushort = 192 KB
#define WPACK_BYTES ((size_t)WPACK_N * 2)
#define NBF_OFF     (WPACK_OFF + WPACK_BYTES)   // 16B-aligned (6858752)

#define FILL_BLOCKS ((NE + 255) / 256)          // 2344
#define CONV_BLOCKS (WPACK_N / 256)             // 384
#define NBF_BLOCKS  ((NN * DD / 8) / 256)       // 3125

__device__ __forceinline__ unsigned short f2bf(float f) {   // RNE fp32->bf16
    unsigned int u = __float_as_uint(f);
    unsigned int r = (u + 0x7fffu + ((u >> 16) & 1u)) >> 16;
    return (unsigned short)r;
}
__device__ __forceinline__ float bf2f(unsigned short h) {
    return __uint_as_float(((unsigned int)h) << 16);
}
__device__ __forceinline__ void accum8(float* x, uint4 v, float msk) {
    x[0] = fmaf(__uint_as_float(v.x << 16),          msk, x[0]);
    x[1] = fmaf(__uint_as_float(v.x & 0xffff0000u),  msk, x[1]);
    x[2] = fmaf(__uint_as_float(v.y << 16),          msk, x[2]);
    x[3] = fmaf(__uint_as_float(v.y & 0xffff0000u),  msk, x[3]);
    x[4] = fmaf(__uint_as_float(v.z << 16),          msk, x[4]);
    x[5] = fmaf(__uint_as_float(v.z & 0xffff0000u),  msk, x[5]);
    x[6] = fmaf(__uint_as_float(v.w << 16),          msk, x[6]);
    x[7] = fmaf(__uint_as_float(v.w & 0xffff0000u),  msk, x[7]);
}

// ---------------- prep: fill buckets + pack weights + nodes->bf16 ----------------
__global__ __launch_bounds__(256) void prep_k(
    const int* __restrict__ adj, int* __restrict__ cnt, unsigned short* __restrict__ slots,
    const float* __restrict__ Wr, const float* __restrict__ Wz,
    const float* __restrict__ Wt, unsigned short* __restrict__ wp,
    const float* __restrict__ nodes, unsigned short* __restrict__ nbf)
{
    int b = blockIdx.x;
    if (b < FILL_BLOCKS) {
        int e = b * 256 + threadIdx.x;
        if (e >= NE) return;
        int d = adj[e];
        int pos = atomicAdd(&cnt[d], 1);
        if (pos < CAP) slots[(size_t)d * CAP + pos] = (unsigned short)adj[NE + e];
        // pos >= CAP: cnt[d] > CAP signals fused_k to take the full-scan path
    } else if (b < FILL_BLOCKS + CONV_BLOCKS) {
        int t = (b - FILL_BLOCKS) * 256 + threadIdx.x;   // [0, 98304)
        int j  = t & 7;
        int l  = (t >> 3) & 63;
        int kt = (t >> 9) & 7;
        int ct = (t >> 12) & 7;
        int g  = t >> 15;
        int k   = kt * 32 + ((l >> 4) & 3) * 8 + j;
        int col = ct * 16 + (l & 15);
        const float* W = (g == 0) ? Wr : (g == 1) ? Wz : Wt;
        wp[t] = f2bf(W[k * DD + col]);
    } else {
        int t = (b - FILL_BLOCKS - CONV_BLOCKS) * 256 + threadIdx.x;  // [0, 800000)
        const float4* s4 = (const float4*)nodes + (size_t)t * 2;
        float4 a = s4[0], c4 = s4[1];
        uint4 o;
        o.x = (unsigned)f2bf(a.x)  | ((unsigned)f2bf(a.y)  << 16);
        o.y = (unsigned)f2bf(a.z)  | ((unsigned)f2bf(a.w)  << 16);
        o.z = (unsigned)f2bf(c4.x) | ((unsigned)f2bf(c4.y) << 16);
        o.w = (unsigned)f2bf(c4.z) | ((unsigned)f2bf(c4.w) << 16);
        ((uint4*)nbf)[t] = o;
    }
}

// ---------------- fused: gather -> softmax -> 3 MFMA GEMMs -> output ----------------
__global__ __launch_bounds__(256) void fused_k(
    const unsigned short* __restrict__ nbf,
    const int* __restrict__ adj,
    const int* __restrict__ cnt,
    const unsigned short* __restrict__ slots,
    const unsigned short* __restrict__ wp,
    const float* __restrict__ bias,
    const float* __restrict__ br, const float* __restrict__ bz, const float* __restrict__ bt,
    float* __restrict__ out)
{
    // X[row][0:128]=s (bf16), X[row][128:256]=ph -> r*ph (bf16); +8 pad
    __shared__ unsigned short X[64][264];       // 33 KB
    __shared__ unsigned short PH[64][128];      // 16 KB: original ph for epilogue
    const int tid  = threadIdx.x;
    const int w    = tid >> 6;                  // wave id: owns rows w*16..w*16+15
    const int l    = tid & 63;
    const int row0 = blockIdx.x * 64;
    const int q    = l >> 4;                    // quarter-wave id
    const int li   = l & 15;                    // lane within quarter: 8 channels 8li..8li+7

    // ---- Phase A: gather agg = sum nbf[src] (+bias), softmax, stage bf16 [s|ph]
    {
        const float4 bb0 = *(const float4*)(bias + 8 * li);
        const float4 bb1 = *(const float4*)(bias + 8 * li + 4);
        int rown = row0 + w * 16 + li;                       // lane li's row (for cnt preload)
        int c_all = cnt[rown < NN ? rown : 0];
        for (int j = 0; j < 16; ++j) {
            int lr   = w * 16 + j;
            int grow = row0 + lr;
            int gc   = grow < NN ? grow : 0;
            int c    = __shfl(c_all, j);
            // ph row (each quarter loads the same 16B/li -> L1 broadcast)
            uint4 phv = *(const uint4*)(nbf + (size_t)gc * DD + 8 * li);
            float x[8];
#pragma unroll
            for (int i = 0; i < 8; ++i) x[i] = 0.f;
            if (c <= CAP) {
                int myslot = (l < c) ? (int)slots[(size_t)gc * CAP + l] : 0;
                // first 16 neighbors: 4 loads x 4 rows, ONE wait
                {
                    uint4 v[4]; float msk[4];
#pragma unroll
                    for (int i = 0; i < 4; ++i) {
                        int sp = i * 4 + q;
                        int s0 = __shfl(myslot, sp);         // sp>=c -> lane holds 0 -> row 0
                        v[i] = *(const uint4*)(nbf + (size_t)s0 * DD + 8 * li);
                        msk[i] = (sp < c) ? 1.f : 0.f;
                    }
#pragma unroll
                    for (int i = 0; i < 4; ++i) accum8(x, v[i], msk[i]);
                }
                for (int jj = 16; jj < c; jj += 16) {        // deg>16: one wait per 16
                    uint4 v[4]; float msk[4];
#pragma unroll
                    for (int i = 0; i < 4; ++i) {
                        int sp = jj + i * 4 + q;
                        int s0 = __shfl(myslot, sp & 63);
                        v[i] = *(const uint4*)(nbf + (size_t)s0 * DD + 8 * li);
                        msk[i] = (sp < c) ? 1.f : 0.f;
                    }
#pragma unroll
                    for (int i = 0; i < 4; ++i) accum8(x, v[i], msk[i]);
                }
            } else {
                // overflow (prob ~0): full edge scan, matches round-robin over quarters
                int mi = 0;
                for (int base = 0; base < NE; base += 64) {
                    int e  = base + l;
                    int d  = (e < NE) ? adj[e] : -1;
                    int sv = (e < NE) ? adj[NE + e] : 0;
                    unsigned long long m = __ballot(d == grow);
                    while (m) {
                        int bpos = __ffsll((unsigned long long)m) - 1;
                        m &= m - 1;
                        int s0 = __shfl(sv, bpos);
                        if ((mi & 3) == q) {
                            uint4 v = *(const uint4*)(nbf + (size_t)s0 * DD + 8 * li);
                            accum8(x, v, 1.f);
                        }
                        ++mi;
                    }
                }
            }
            // combine quarter partial sums, add bias
#pragma unroll
            for (int i = 0; i < 8; ++i) {
                x[i] += __shfl_xor(x[i], 16);
                x[i] += __shfl_xor(x[i], 32);
            }
            x[0] += bb0.x; x[1] += bb0.y; x[2] += bb0.z; x[3] += bb0.w;
            x[4] += bb1.x; x[5] += bb1.y; x[6] += bb1.z; x[7] += bb1.w;
            // softmax over 128 channels (8/lane x 16 lanes, replicated across quarters)
            float mx = x[0];
#pragma unroll
            for (int i = 1; i < 8; ++i) mx = fmaxf(mx, x[i]);
#pragma unroll
            for (int o = 1; o < 16; o <<= 1) mx = fmaxf(mx, __shfl_xor(mx, o));
            float e8[8], sm = 0.f;
#pragma unroll
            for (int i = 0; i < 8; ++i) { e8[i] = __expf(x[i] - mx); sm += e8[i]; }
#pragma unroll
            for (int o = 1; o < 16; o <<= 1) sm += __shfl_xor(sm, o);
            float inv = 1.f / sm;
            if (q == 0) {
                uint4 u;
                u.x = (unsigned)f2bf(e8[0] * inv) | ((unsigned)f2bf(e8[1] * inv) << 16);
                u.y = (unsigned)f2bf(e8[2] * inv) | ((unsigned)f2bf(e8[3] * inv) << 16);
                u.z = (unsigned)f2bf(e8[4] * inv) | ((unsigned)f2bf(e8[5] * inv) << 16);
                u.w = (unsigned)f2bf(e8[6] * inv) | ((unsigned)f2bf(e8[7] * inv) << 16);
                *(uint4*)&X[lr][8 * li] = u;
            } else if (q == 1) {
                *(uint4*)&X[lr][128 + 8 * li] = phv;
            } else if (q == 2) {
                *(uint4*)&PH[lr][8 * li] = phv;
            }
        }
    }
    // NO __syncthreads: each wave reads only the 16 rows it just wrote.

    // ---- Phase B: MFMA GEMMs. Wave w owns row tile rt=w.
    const int rbase  = w * 16;
    const int mrow   = l & 15;      // A-frag row within tile
    const int quad   = l >> 4;      // A/B-frag k-quad
    const int col_in = l & 15;      // C/D col within tile
    const int rq     = l >> 4;      // C/D row quad

    s16x8 a[8];                      // A-frags for K=256 (8 x 32)
#pragma unroll
    for (int kt = 0; kt < 8; ++kt)
        a[kt] = *(const s16x8*)&X[rbase + mrow][kt * 32 + quad * 8];

    const s16x8* wp8 = (const s16x8*)wp;
    float zv[8][4];

    // r and z over all 8 col-tiles; write r*ph back into X ph-half
#pragma unroll
    for (int ct = 0; ct < 8; ++ct) {
        int c = ct * 16 + col_in;
        float brv = br[c], bzv = bz[c];
        f32x4 ar = {brv, brv, brv, brv};
        f32x4 az = {bzv, bzv, bzv, bzv};
#pragma unroll
        for (int kt = 0; kt < 8; ++kt) {
            s16x8 bfr = wp8[((0 * 8 + ct) * 8 + kt) * 64 + l];
            s16x8 bfz = wp8[((1 * 8 + ct) * 8 + kt) * 64 + l];
            ar = __builtin_amdgcn_mfma_f32_16x16x32_bf16(a[kt], bfr, ar, 0, 0, 0);
            az = __builtin_amdgcn_mfma_f32_16x16x32_bf16(a[kt], bfz, az, 0, 0, 0);
        }
#pragma unroll
        for (int i = 0; i < 4; ++i) {
            float rr = 1.f / (1.f + __expf(-ar[i]));
            zv[ct][i] = 1.f / (1.f + __expf(-az[i]));
            int lr = rbase + rq * 4 + i;
            float ph = bf2f(X[lr][128 + c]);
            X[lr][128 + c] = f2bf(rr * ph);       // same-wave rows only
        }
    }

    // reload A-frags covering the (now r*ph) half
#pragma unroll
    for (int kt = 4; kt < 8; ++kt)
        a[kt] = *(const s16x8*)&X[rbase + mrow][kt * 32 + quad * 8];

    // t GEMM + epilogue
#pragma unroll
    for (int ct = 0; ct < 8; ++ct) {
        int c = ct * 16 + col_in;
        float btv = bt[c];
        f32x4 at = {btv, btv, btv, btv};
#pragma unroll
        for (int kt = 0; kt < 8; ++kt) {
            s16x8 bft = wp8[((2 * 8 + ct) * 8 + kt) * 64 + l];
            at = __builtin_amdgcn_mfma_f32_16x16x32_bf16(a[kt], bft, at, 0, 0, 0);
        }
#pragma unroll
        for (int i = 0; i < 4; ++i) {
            int lr   = rbase + rq * 4 + i;
            int grow = row0 + lr;
            if (grow < NN) {
                float hh = tanhf(at[i]);
                float z  = zv[ct][i];
                float ph = bf2f(PH[lr][c]);
                out[(size_t)grow * DD + c] = (1.f - z) * ph + z * hh;
            }
        }
    }
}

extern "C" void kernel_launch(void* const* d_in, const int* in_sizes, int n_in,
                              void* d_out, int out_size, void* d_ws, size_t ws_size,
                              hipStream_t stream) {
    const float* nodes = (const float*)d_in[0];
    const int*   adj   = (const int*)d_in[1];
    const float* bias  = (const float*)d_in[2];
    const float* Wr    = (const float*)d_in[3];
    const float* br    = (const float*)d_in[4];
    const float* Wz    = (const float*)d_in[5];
    const float* bz    = (const float*)d_in[6];
    const float* Wt    = (const float*)d_in[7];
    const float* bt    = (const float*)d_in[8];
    float* out = (float*)d_out;

    char* ws = (char*)d_ws;
    int*            cnt   = (int*)ws;
    unsigned short* slots = (unsigned short*)(ws + SLOT_OFF);
    unsigned short* wpack = (unsigned short*)(ws + WPACK_OFF);
    unsigned short* nbf   = (unsigned short*)(ws + NBF_OFF);
    // ws need ~19.7 MB; observed ws_size ~27.5 MB.

    hipMemsetAsync(cnt, 0, (size_t)NN * sizeof(int), stream);

    // Reference never updates prior_h inside its loop -> all 4 steps identical;
    // one propagation step suffices.
    prep_k<<<FILL_BLOCKS + CONV_BLOCKS + NBF_BLOCKS, 256, 0, stream>>>(
        adj, cnt, slots, Wr, Wz, Wt, wpack, nodes, nbf);
    fused_k<<<(NN + 63) / 64, 256, 0, stream>>>(nbf, adj, cnt, slots, wpack,
                                                bias, br, bz, bt, out);
}

// Round 7
// 205.246 us; speedup vs baseline: 6.4063x; 1.1919x over previous
//
#include <hip/hip_runtime.h>

#define NN 50000
#define NE 600000
#define DD 128
#define CAP 64

typedef __attribute__((ext_vector_type(8))) short s16x8;   // 8 bf16 (4 VGPRs)
typedef __attribute__((ext_vector_type(4))) float f32x4;   // MFMA accumulator

// d_ws layout (bytes):
//   [0, 256K)       : int cnt[NN]                (memset to 0 each launch)
//   [SLOT_OFF, +6.4M): ushort slots[NN*CAP]
//   [WPACK_OFF,+192K): ushort wpack[3*8*8*512]   (B-fragment-packed bf16 weights)
//   [NBF_OFF, +12.8M): ushort nbf[NN*DD]         (bf16 copy of nodes)
#define CNT_BYTES   (256 * 1024)
#define SLOT_OFF    CNT_BYTES
#define SLOT_BYTES  ((size_t)NN * CAP * 2)
#define WPACK_OFF   (SLOT_OFF + SLOT_BYTES)
#define WPACK_N     (3 * 8 * 8 * 512)           // 98304 ushort = 192 KB
#define WPACK_BYTES ((size_t)WPACK_N * 2)
#define NBF_OFF     (WPACK_OFF + WPACK_BYTES)   // 16B-aligned

#define FILL_BLOCKS ((NE / 2 + 255) / 256)      // 1172 (2 edges/thread)
#define CONV_BLOCKS (WPACK_N / 256)             // 384
#define NBF_BLOCKS  ((NN * DD / 8) / 256)       // 3125

__device__ __forceinline__ unsigned short f2bf(float f) {   // RNE fp32->bf16
    unsigned int u = __float_as_uint(f);
    unsigned int r = (u + 0x7fffu + ((u >> 16) & 1u)) >> 16;
    return (unsigned short)r;
}
__device__ __forceinline__ float bf2f(unsigned short h) {
    return __uint_as_float(((unsigned int)h) << 16);
}
__device__ __forceinline__ void accum8(float* x, uint4 v, float msk) {
    x[0] = fmaf(__uint_as_float(v.x << 16),          msk, x[0]);
    x[1] = fmaf(__uint_as_float(v.x & 0xffff0000u),  msk, x[1]);
    x[2] = fmaf(__uint_as_float(v.y << 16),          msk, x[2]);
    x[3] = fmaf(__uint_as_float(v.y & 0xffff0000u),  msk, x[3]);
    x[4] = fmaf(__uint_as_float(v.z << 16),          msk, x[4]);
    x[5] = fmaf(__uint_as_float(v.z & 0xffff0000u),  msk, x[5]);
    x[6] = fmaf(__uint_as_float(v.w << 16),          msk, x[6]);
    x[7] = fmaf(__uint_as_float(v.w & 0xffff0000u),  msk, x[7]);
}

// ---------------- prep: fill buckets (2 edges/thr) + pack weights + nodes->bf16 ----
__global__ __launch_bounds__(256) void prep_k(
    const int* __restrict__ adj, int* __restrict__ cnt, unsigned short* __restrict__ slots,
    const float* __restrict__ Wr, const float* __restrict__ Wz,
    const float* __restrict__ Wt, unsigned short* __restrict__ wp,
    const float* __restrict__ nodes, unsigned short* __restrict__ nbf)
{
    int b = blockIdx.x;
    if (b < FILL_BLOCKS) {
        int t = b * 256 + threadIdx.x;
        if (2 * t >= NE) return;
        int2 d2 = *(const int2*)(adj + 2 * t);
        int2 s2 = *(const int2*)(adj + NE + 2 * t);
        int p0 = atomicAdd(&cnt[d2.x], 1);
        if (p0 < CAP) slots[(size_t)d2.x * CAP + p0] = (unsigned short)s2.x;
        int p1 = atomicAdd(&cnt[d2.y], 1);
        if (p1 < CAP) slots[(size_t)d2.y * CAP + p1] = (unsigned short)s2.y;
        // pos >= CAP: cnt[d] > CAP signals fused_k to take the full-scan path
    } else if (b < FILL_BLOCKS + CONV_BLOCKS) {
        int t = (b - FILL_BLOCKS) * 256 + threadIdx.x;   // [0, 98304)
        int j  = t & 7;
        int l  = (t >> 3) & 63;
        int kt = (t >> 9) & 7;
        int ct = (t >> 12) & 7;
        int g  = t >> 15;
        int k   = kt * 32 + ((l >> 4) & 3) * 8 + j;
        int col = ct * 16 + (l & 15);
        const float* W = (g == 0) ? Wr : (g == 1) ? Wz : Wt;
        wp[t] = f2bf(W[k * DD + col]);
    } else {
        int t = (b - FILL_BLOCKS - CONV_BLOCKS) * 256 + threadIdx.x;  // [0, 800000)
        const float4* s4 = (const float4*)nodes + (size_t)t * 2;
        float4 a = s4[0], c4 = s4[1];
        uint4 o;
        o.x = (unsigned)f2bf(a.x)  | ((unsigned)f2bf(a.y)  << 16);
        o.y = (unsigned)f2bf(a.z)  | ((unsigned)f2bf(a.w)  << 16);
        o.z = (unsigned)f2bf(c4.x) | ((unsigned)f2bf(c4.y) << 16);
        o.w = (unsigned)f2bf(c4.z) | ((unsigned)f2bf(c4.w) << 16);
        ((uint4*)nbf)[t] = o;
    }
}

// ---------------- fused: pipelined gather -> softmax -> 3 MFMA GEMMs -> output ----
__global__ __launch_bounds__(256, 4) void fused_k(
    const unsigned short* __restrict__ nbf,
    const int* __restrict__ adj,
    const int* __restrict__ cnt,
    const unsigned short* __restrict__ slots,
    const unsigned short* __restrict__ wp,
    const float* __restrict__ bias,
    const float* __restrict__ br, const float* __restrict__ bz, const float* __restrict__ bt,
    float* __restrict__ out)
{
    // X[row][0:128]=s (bf16) -> later r*ph; X[row][128:256]=ph (bf16, kept); +8 pad
    __shared__ unsigned short X[64][264];       // 33.8 KB (only LDS array)
    const int tid  = threadIdx.x;
    const int w    = tid >> 6;                  // wave id: owns rows w*16..w*16+15
    const int l    = tid & 63;
    const int row0 = blockIdx.x * 64;
    const int q    = l >> 4;                    // quarter-wave id
    const int li   = l & 15;                    // lane in quarter: channels 8li..8li+7

    // ---- Phase A: 2-deep pipelined gather + softmax, stage bf16 [s|ph] in LDS
    {
        const float4 bb0 = *(const float4*)(bias + 8 * li);
        const float4 bb1 = *(const float4*)(bias + 8 * li + 4);
        int rown  = row0 + (w << 4) + li;
        int c_all = cnt[rown < NN ? rown : 0];

        unsigned short sraw[2];                 // pending slot loads (rows j+1, j+2)
        uint4 vg[2][4]; float mg[2][4];         // pending gathers (rows j, j+1)
        uint4 phg[2];                           // pending ph loads
        int   slotm[2], cj[2];

        // prologue: slot loads for rows 0,1; gathers for row 0
        {
            int g0 = row0 + (w << 4);
            int gc0 = g0 < NN ? g0 : 0;
            int gc1 = (g0 + 1) < NN ? (g0 + 1) : 0;
            sraw[0] = slots[(size_t)gc0 * CAP + l];
            sraw[1] = slots[(size_t)gc1 * CAP + l];
            cj[0] = __shfl(c_all, 0);
            slotm[0] = (l < cj[0]) ? (int)sraw[0] : 0;
            if (q == 1) phg[0] = *(const uint4*)(nbf + (size_t)gc0 * DD + 8 * li);
#pragma unroll
            for (int i = 0; i < 4; ++i) {
                int sp = i * 4 + q;
                int s0 = __shfl(slotm[0], sp);
                vg[0][i] = *(const uint4*)(nbf + (size_t)s0 * DD + 8 * li);
                mg[0][i] = (sp < cj[0]) ? 1.f : 0.f;
            }
        }

#pragma unroll
        for (int j = 0; j < 16; ++j) {
            const int p = j & 1, pn = p ^ 1;
            // issue slot load for row j+2
            unsigned short snew = 0;
            if (j + 2 < 16) {
                int g2 = row0 + (w << 4) + j + 2;
                int gc2 = g2 < NN ? g2 : 0;
                snew = slots[(size_t)gc2 * CAP + l];
            }
            // issue gathers for row j+1 (slot load issued 2 iters ago)
            if (j + 1 < 16) {
                int g1 = row0 + (w << 4) + j + 1;
                int gc1 = g1 < NN ? g1 : 0;
                cj[pn] = __shfl(c_all, j + 1);
                slotm[pn] = (l < cj[pn]) ? (int)sraw[pn] : 0;
                if (q == 1) phg[pn] = *(const uint4*)(nbf + (size_t)gc1 * DD + 8 * li);
#pragma unroll
                for (int i = 0; i < 4; ++i) {
                    int sp = i * 4 + q;
                    int s0 = __shfl(slotm[pn], sp);
                    vg[pn][i] = *(const uint4*)(nbf + (size_t)s0 * DD + 8 * li);
                    mg[pn][i] = (sp < cj[pn]) ? 1.f : 0.f;
                }
            }
            // ---- combine row j
            int lr   = (w << 4) + j;
            int grow = row0 + lr;
            int c    = cj[p];
            float x[8];
#pragma unroll
            for (int i = 0; i < 8; ++i) x[i] = 0.f;
            if (c <= CAP) {
#pragma unroll
                for (int i = 0; i < 4; ++i) accum8(x, vg[p][i], mg[p][i]);
                for (int jj = 16; jj < c; jj += 16) {        // deg>16 tail (~10% rows)
                    uint4 v[4]; float msk[4];
#pragma unroll
                    for (int i = 0; i < 4; ++i) {
                        int sp = jj + i * 4 + q;
                        int s0 = __shfl(slotm[p], sp & 63);
                        v[i] = *(const uint4*)(nbf + (size_t)s0 * DD + 8 * li);
                        msk[i] = (sp < c) ? 1.f : 0.f;
                    }
#pragma unroll
                    for (int i = 0; i < 4; ++i) accum8(x, v[i], msk[i]);
                }
            } else {
                // overflow (prob ~0): full edge scan, matches round-robin over quarters
                int mi = 0;
                for (int base = 0; base < NE; base += 64) {
                    int e  = base + l;
                    int d  = (e < NE) ? adj[e] : -1;
                    int sv = (e < NE) ? adj[NE + e] : 0;
                    unsigned long long m = __ballot(d == grow);
                    while (m) {
                        int bpos = __ffsll((unsigned long long)m) - 1;
                        m &= m - 1;
                        int s0 = __shfl(sv, bpos);
                        if ((mi & 3) == q) {
                            uint4 v = *(const uint4*)(nbf + (size_t)s0 * DD + 8 * li);
                            accum8(x, v, 1.f);
                        }
                        ++mi;
                    }
                }
            }
            // combine quarter partial sums, add bias
#pragma unroll
            for (int i = 0; i < 8; ++i) {
                x[i] += __shfl_xor(x[i], 16);
                x[i] += __shfl_xor(x[i], 32);
            }
            x[0] += bb0.x; x[1] += bb0.y; x[2] += bb0.z; x[3] += bb0.w;
            x[4] += bb1.x; x[5] += bb1.y; x[6] += bb1.z; x[7] += bb1.w;
            // softmax over 128 channels (8/lane x 16 lanes, replicated across quarters)
            float mx = x[0];
#pragma unroll
            for (int i = 1; i < 8; ++i) mx = fmaxf(mx, x[i]);
#pragma unroll
            for (int o = 1; o < 16; o <<= 1) mx = fmaxf(mx, __shfl_xor(mx, o));
            float e8[8], sm = 0.f;
#pragma unroll
            for (int i = 0; i < 8; ++i) { e8[i] = __expf(x[i] - mx); sm += e8[i]; }
#pragma unroll
            for (int o = 1; o < 16; o <<= 1) sm += __shfl_xor(sm, o);
            float inv = 1.f / sm;
            if (q == 0) {
                uint4 u;
                u.x = (unsigned)f2bf(e8[0] * inv) | ((unsigned)f2bf(e8[1] * inv) << 16);
                u.y = (unsigned)f2bf(e8[2] * inv) | ((unsigned)f2bf(e8[3] * inv) << 16);
                u.z = (unsigned)f2bf(e8[4] * inv) | ((unsigned)f2bf(e8[5] * inv) << 16);
                u.w = (unsigned)f2bf(e8[6] * inv) | ((unsigned)f2bf(e8[7] * inv) << 16);
                *(uint4*)&X[lr][8 * li] = u;
            } else if (q == 1) {
                *(uint4*)&X[lr][128 + 8 * li] = phg[p];
            }
            sraw[p] = snew;     // row j+2 has parity p
        }
    }
    // NO __syncthreads: each wave reads only the 16 rows it just wrote.

    // ---- Phase B: MFMA GEMMs. Wave w owns row tile rt=w.
    const int rbase  = w * 16;
    const int mrow   = l & 15;      // A-frag row within tile
    const int quad   = l >> 4;      // A/B-frag k-quad
    const int col_in = l & 15;      // C/D col within tile
    const int rq     = l >> 4;      // C/D row quad

    s16x8 a[8];                      // A-frags for K=256 (8 x 32)
#pragma unroll
    for (int kt = 0; kt < 8; ++kt)
        a[kt] = *(const s16x8*)&X[rbase + mrow][kt * 32 + quad * 8];

    const s16x8* wp8 = (const s16x8*)wp;
    float zv[8][4];

    // r and z over all 8 col-tiles; write r*ph into the (dead) s-half of X,
    // preserving original ph in the ph-half for the epilogue.
#pragma unroll
    for (int ct = 0; ct < 8; ++ct) {
        int c = ct * 16 + col_in;
        float brv = br[c], bzv = bz[c];
        f32x4 ar = {brv, brv, brv, brv};
        f32x4 az = {bzv, bzv, bzv, bzv};
#pragma unroll
        for (int kt = 0; kt < 8; ++kt) {
            s16x8 bfr = wp8[((0 * 8 + ct) * 8 + kt) * 64 + l];
            s16x8 bfz = wp8[((1 * 8 + ct) * 8 + kt) * 64 + l];
            ar = __builtin_amdgcn_mfma_f32_16x16x32_bf16(a[kt], bfr, ar, 0, 0, 0);
            az = __builtin_amdgcn_mfma_f32_16x16x32_bf16(a[kt], bfz, az, 0, 0, 0);
        }
#pragma unroll
        for (int i = 0; i < 4; ++i) {
            float rr = 1.f / (1.f + __expf(-ar[i]));
            zv[ct][i] = 1.f / (1.f + __expf(-az[i]));
            int lr = rbase + rq * 4 + i;
            float ph = bf2f(X[lr][128 + c]);
            X[lr][c] = f2bf(rr * ph);             // same-wave rows only; s-half is dead
        }
    }

    // reload A-frags kt=4..7 (r*ph) from the s-half
#pragma unroll
    for (int kt = 4; kt < 8; ++kt)
        a[kt] = *(const s16x8*)&X[rbase + mrow][(kt - 4) * 32 + quad * 8];

    // t GEMM + epilogue
#pragma unroll
    for (int ct = 0; ct < 8; ++ct) {
        int c = ct * 16 + col_in;
        float btv = bt[c];
        f32x4 at = {btv, btv, btv, btv};
#pragma unroll
        for (int kt = 0; kt < 8; ++kt) {
            s16x8 bft = wp8[((2 * 8 + ct) * 8 + kt) * 64 + l];
            at = __builtin_amdgcn_mfma_f32_16x16x32_bf16(a[kt], bft, at, 0, 0, 0);
        }
#pragma unroll
        for (int i = 0; i < 4; ++i) {
            int lr   = rbase + rq * 4 + i;
            int grow = row0 + lr;
            if (grow < NN) {
                float hh = tanhf(at[i]);
                float z  = zv[ct][i];
                float ph = bf2f(X[lr][128 + c]);  // original ph (bf16), preserved
                out[(size_t)grow * DD + c] = (1.f - z) * ph + z * hh;
            }
        }
    }
}

extern "C" void kernel_launch(void* const* d_in, const int* in_sizes, int n_in,
                              void* d_out, int out_size, void* d_ws, size_t ws_size,
                              hipStream_t stream) {
    const float* nodes = (const float*)d_in[0];
    const int*   adj   = (const int*)d_in[1];
    const float* bias  = (const float*)d_in[2];
    const float* Wr    = (const float*)d_in[3];
    const float* br    = (const float*)d_in[4];
    const float* Wz    = (const float*)d_in[5];
    const float* bz    = (const float*)d_in[6];
    const float* Wt    = (const float*)d_in[7];
    const float* bt    = (const float*)d_in[8];
    float* out = (float*)d_out;

    char* ws = (char*)d_ws;
    int*            cnt   = (int*)ws;
    unsigned short* slots = (unsigned short*)(ws + SLOT_OFF);
    unsigned short* wpack = (unsigned short*)(ws + WPACK_OFF);
    unsigned short* nbf   = (unsigned short*)(ws + NBF_OFF);

    hipMemsetAsync(cnt, 0, (size_t)NN * sizeof(int), stream);

    // Reference never updates prior_h inside its loop -> all 4 steps identical;
    // one propagation step suffices.
    prep_k<<<FILL_BLOCKS + CONV_BLOCKS + NBF_BLOCKS, 256, 0, stream>>>(
        adj, cnt, slots, Wr, Wz, Wt, wpack, nodes, nbf);
    fused_k<<<(NN + 63) / 64, 256, 0, stream>>>(nbf, adj, cnt, slots, wpack,
                                                bias, br, bz, bt, out);
}